// Round 1
// baseline (1024.467 us; speedup 1.0000x reference)
//
#include <hip/hip_runtime.h>
#include <cstdint>
#include <cstddef>

#define NE 8
#define DMODEL 768
#define MLPDIM 3072
#define NDET 16384
#define NCLS 4096
#define NTOK 20480
#define ROWS_PER_E 5120   /* 16*256 (det) + 8*128 (cls) */
#define TOT_ROWS 40960

typedef float f32x4 __attribute__((ext_vector_type(4)));
typedef __bf16 bf16x8 __attribute__((ext_vector_type(8)));

__device__ __forceinline__ unsigned short f2bf(float f) {
    unsigned u = __float_as_uint(f);
    u += 0x7FFFu + ((u >> 16) & 1u);   // RNE
    return (unsigned short)(u >> 16);
}
__device__ __forceinline__ float bf2f(unsigned v) {
    return __uint_as_float(v << 16);
}
__device__ __forceinline__ float gelu_f(float x) {
    // jax.nn.gelu approximate=True (tanh form)
    float u = 0.7978845608028654f * (x + 0.044715f * x * x * x);
    float a = fabsf(u);
    float t = __expf(-2.0f * a);
    float th = (1.0f - t) / (1.0f + t);
    th = (u >= 0.0f) ? th : -th;
    return 0.5f * x * (1.0f + th);
}

// ---------------- x -> bf16 ----------------
__global__ void k_convert_x(const float* __restrict__ xd, const float* __restrict__ xc,
                            ushort* __restrict__ xbf) {
    long i = ((long)blockIdx.x * 256 + threadIdx.x) * 8;
    const long nd = (long)NDET * DMODEL;
    const long nt = (long)NTOK * DMODEL;
    if (i >= nt) return;
    const float* src = (i < nd) ? (xd + i) : (xc + (i - nd));
    float4 f0 = *(const float4*)(src);
    float4 f1 = *(const float4*)(src + 4);
    uint4 o;
    o.x = (unsigned)f2bf(f0.x) | ((unsigned)f2bf(f0.y) << 16);
    o.y = (unsigned)f2bf(f0.z) | ((unsigned)f2bf(f0.w) << 16);
    o.z = (unsigned)f2bf(f1.x) | ((unsigned)f2bf(f1.y) << 16);
    o.w = (unsigned)f2bf(f1.z) | ((unsigned)f2bf(f1.w) << 16);
    *(uint4*)(xbf + i) = o;
}

// ---------------- w [E][K][N] fp32 -> [E][N][K] bf16 ----------------
__global__ void k_transpose_bf(const float* __restrict__ in, ushort* __restrict__ out,
                               int K, int N) {
    __shared__ float tile[32][33];
    int e = blockIdx.z;
    const float* A = in + (size_t)e * K * N;
    ushort* B = out + (size_t)e * N * K;
    int n0 = blockIdx.x * 32, k0 = blockIdx.y * 32;
    for (int i = threadIdx.y; i < 32; i += 8)
        tile[i][threadIdx.x] = A[(size_t)(k0 + i) * N + n0 + threadIdx.x];
    __syncthreads();
    for (int i = threadIdx.y; i < 32; i += 8)
        B[(size_t)(n0 + i) * K + k0 + threadIdx.x] = f2bf(tile[threadIdx.x][i]);
}

// ---------------- router: one wave per token, fp32 ----------------
__global__ void k_router(const float* __restrict__ xd, const float* __restrict__ xc,
                         const float* __restrict__ wrd, const float* __restrict__ wrc,
                         int* __restrict__ e1, int* __restrict__ e2,
                         float* __restrict__ g1, float* __restrict__ g2) {
    int wave = threadIdx.x >> 6, lane = threadIdx.x & 63;
    int t = blockIdx.x * 4 + wave;
    if (t >= NTOK) return;
    const float* xrow;
    const float* w;
    if (t < NDET) { xrow = xd + (size_t)t * DMODEL; w = wrd; }
    else          { xrow = xc + (size_t)(t - NDET) * DMODEL; w = wrc; }
    float acc[8];
    #pragma unroll
    for (int e = 0; e < 8; e++) acc[e] = 0.0f;
    for (int k = lane; k < DMODEL; k += 64) {
        float xv = xrow[k];
        const float* wr = w + k * 8;
        #pragma unroll
        for (int e = 0; e < 8; e++) acc[e] += xv * wr[e];
    }
    #pragma unroll
    for (int e = 0; e < 8; e++) {
        #pragma unroll
        for (int off = 32; off > 0; off >>= 1) acc[e] += __shfl_xor(acc[e], off);
    }
    // all lanes hold full logits; top-2 with lower-index tie-break (lax.top_k)
    int i1 = 0; float v1 = acc[0];
    #pragma unroll
    for (int e = 1; e < 8; e++) if (acc[e] > v1) { v1 = acc[e]; i1 = e; }
    int i2 = -1; float v2 = -1e30f;
    #pragma unroll
    for (int e = 0; e < 8; e++) if (e != i1 && acc[e] > v2) { v2 = acc[e]; i2 = e; }
    float Z = 0.0f;
    #pragma unroll
    for (int e = 0; e < 8; e++) Z += __expf(acc[e] - v1);
    if (lane == 0) {
        e1[t] = i1; e2[t] = i2;
        g1[t] = 1.0f / Z;
        g2[t] = __expf(v2 - v1) / Z;
    }
}

// ---------------- capacity scan: one wave per group, k-major order ----------------
__global__ void k_scan(const int* __restrict__ e1, const int* __restrict__ e2,
                       int* __restrict__ slot_map, int* __restrict__ r1, int* __restrict__ r2) {
    int g = blockIdx.x;          // 0..15 det, 16..23 cls
    int lane = threadIdx.x;      // 64 threads
    int S, C, base;
    if (g < 16) { S = 1024; C = 256; base = g * 1024; }
    else        { S = 512;  C = 128; base = NDET + (g - 16) * 512; }
    int cnt[8];
    #pragma unroll
    for (int e = 0; e < 8; e++) cnt[e] = 0;
    unsigned long long lower = (lane == 0) ? 0ULL : ((~0ULL) >> (64 - lane));
    int nch = (2 * S) >> 6;
    for (int ch = 0; ch < nch; ch++) {
        int n = ch * 64 + lane;
        int k = (n >= S) ? 1 : 0;
        int s = n - k * S;
        int tok = base + s;
        int e = k ? e2[tok] : e1[tok];
        int pos = 0;
        #pragma unroll
        for (int ee = 0; ee < 8; ee++) {
            unsigned long long m = __ballot(e == ee);
            if (e == ee) pos = cnt[ee] + __popcll(m & lower);
            cnt[ee] += __popcll(m);
        }
        int r = -1;
        if (pos < C) {
            int local = (g < 16) ? (g * 256 + pos) : (4096 + (g - 16) * 128 + pos);
            r = e * ROWS_PER_E + local;
            slot_map[r] = tok;
        }
        if (k == 0) r1[tok] = r; else r2[tok] = r;
    }
}

// ---------------- grouped GEMM: C = op(A @ B^T_layout + bias) ----------------
// A: [M=5120][KTOT] bf16 (gather rows via smap if smap!=nullptr; -1 row -> zeros)
// Bt: [NTOT][KTOT] bf16 (pre-transposed weights)
// Cout: [M][NTOT] bf16 (gelu applied if GELU)
template<int KTOT, int NTOT, bool GELU>
__global__ __launch_bounds__(256, 2) void k_gemm(
    const ushort* __restrict__ Asrc, const int* __restrict__ smap,
    const ushort* __restrict__ Bt, const float* __restrict__ bias,
    ushort* __restrict__ Cout) {
    constexpr int KSTEPS = KTOT / 32;
    __shared__ ushort As[128 * 40];   // 40-elem rows: pad to break bank conflicts
    __shared__ ushort Bs[128 * 40];
    const int m0 = blockIdx.x * 128, n0 = blockIdx.y * 128;
    const int t = threadIdx.x, lane = t & 63, wave = t >> 6;
    const int wr = wave >> 1, wc = wave & 1;
    const int srow = t >> 1, half = t & 1;

    const ushort* aptr;
    if (smap) {
        int tok = smap[m0 + srow];
        aptr = (tok >= 0) ? (Asrc + (size_t)tok * KTOT + half * 16) : (const ushort*)nullptr;
    } else {
        aptr = Asrc + (size_t)(m0 + srow) * KTOT + half * 16;
    }
    const ushort* bptr = Bt + (size_t)(n0 + srow) * KTOT + half * 16;

    f32x4 acc[4][4] = {};
    uint4 ra0, ra1, rb0, rb1;

    auto LOAD = [&](int ks) {
        if (aptr) {
            const uint4* ap = (const uint4*)(aptr + ks * 32);
            ra0 = ap[0]; ra1 = ap[1];
        } else {
            ra0 = make_uint4(0, 0, 0, 0); ra1 = make_uint4(0, 0, 0, 0);
        }
        const uint4* bp = (const uint4*)(bptr + ks * 32);
        rb0 = bp[0]; rb1 = bp[1];
    };
    auto WRITE = [&]() {
        uint4* aw = (uint4*)(As + srow * 40 + half * 16);
        aw[0] = ra0; aw[1] = ra1;
        uint4* bw = (uint4*)(Bs + srow * 40 + half * 16);
        bw[0] = rb0; bw[1] = rb1;
    };

    LOAD(0);
    for (int ks = 0; ks < KSTEPS; ks++) {
        __syncthreads();          // previous compute done; LDS reusable
        WRITE();
        __syncthreads();
        if (ks + 1 < KSTEPS) LOAD(ks + 1);   // overlap next loads with MFMA
        const int koff = (lane >> 4) * 8;
        const int ar = wr * 64 + (lane & 15);
        const int br = wc * 64 + (lane & 15);
        bf16x8 af[4], bfr[4];
        #pragma unroll
        for (int mt = 0; mt < 4; mt++)
            af[mt] = *(const bf16x8*)(As + (ar + mt * 16) * 40 + koff);
        #pragma unroll
        for (int nt = 0; nt < 4; nt++)
            bfr[nt] = *(const bf16x8*)(Bs + (br + nt * 16) * 40 + koff);
        #pragma unroll
        for (int mt = 0; mt < 4; mt++) {
            #pragma unroll
            for (int nt = 0; nt < 4; nt++)
                acc[mt][nt] = __builtin_amdgcn_mfma_f32_16x16x32_bf16(af[mt], bfr[nt], acc[mt][nt], 0, 0, 0);
        }
    }

    // epilogue: C/D layout col=lane&15, row=(lane>>4)*4+j
    const int crow_base = m0 + wr * 64;
    const int ccol_base = n0 + wc * 64;
    #pragma unroll
    for (int nt = 0; nt < 4; nt++) {
        int col = ccol_base + nt * 16 + (lane & 15);
        float bv = bias[col];
        #pragma unroll
        for (int mt = 0; mt < 4; mt++) {
            #pragma unroll
            for (int j = 0; j < 4; j++) {
                int row = crow_base + mt * 16 + (lane >> 4) * 4 + j;
                float v = acc[mt][nt][j] + bv;
                if (GELU) v = gelu_f(v);
                Cout[(size_t)row * NTOT + col] = f2bf(v);
            }
        }
    }
}

// ---------------- combine: out[token] = g1*y[r1] + g2*y[r2] ----------------
__global__ void k_combine(const ushort* __restrict__ y,
                          const int* __restrict__ r1, const int* __restrict__ r2,
                          const float* __restrict__ g1, const float* __restrict__ g2,
                          float* __restrict__ out) {
    int t = blockIdx.x;
    int d = threadIdx.x;          // 192 threads, 4 floats each
    int a = r1[t], b = r2[t];
    float wa = g1[t], wb = g2[t];
    size_t opos;
    if (t < NDET) { int bb = t >> 10, s = t & 1023; opos = ((size_t)bb * 1280 + s) * 768; }
    else { int tt = t - NDET; int bb = tt >> 8, s = tt & 255; opos = ((size_t)bb * 1280 + 1024 + s) * 768; }
    int di = d * 4;
    float4 o = make_float4(0.f, 0.f, 0.f, 0.f);
    if (a >= 0) {
        uint2 v = *(const uint2*)(y + (size_t)a * 768 + di);
        o.x += wa * bf2f(v.x & 0xffffu); o.y += wa * bf2f(v.x >> 16);
        o.z += wa * bf2f(v.y & 0xffffu); o.w += wa * bf2f(v.y >> 16);
    }
    if (b >= 0) {
        uint2 v = *(const uint2*)(y + (size_t)b * 768 + di);
        o.x += wb * bf2f(v.x & 0xffffu); o.y += wb * bf2f(v.x >> 16);
        o.z += wb * bf2f(v.y & 0xffffu); o.w += wb * bf2f(v.y >> 16);
    }
    *(float4*)(out + opos + di) = o;
}

extern "C" void kernel_launch(void* const* d_in, const int* in_sizes, int n_in,
                              void* d_out, int out_size, void* d_ws, size_t ws_size,
                              hipStream_t stream) {
    const float* xd  = (const float*)d_in[0];
    const float* xc  = (const float*)d_in[1];
    const float* wrd = (const float*)d_in[2];
    const float* wrc = (const float*)d_in[3];
    const float* w1  = (const float*)d_in[4];
    const float* b1  = (const float*)d_in[5];
    const float* w2  = (const float*)d_in[6];
    const float* b2  = (const float*)d_in[7];
    float* out = (float*)d_out;

    char* p = (char*)d_ws;
    ushort* xbf = (ushort*)p; p += (size_t)NTOK * DMODEL * 2;          // 31.5 MB
    ushort* w1t = (ushort*)p; p += (size_t)NE * MLPDIM * DMODEL * 2;   // 37.7 MB
    ushort* w2t = (ushort*)p; p += (size_t)NE * DMODEL * MLPDIM * 2;   // 37.7 MB
    ushort* h   = (ushort*)p; p += (size_t)ROWS_PER_E * MLPDIM * 2;    // 31.5 MB (per-expert reuse)
    ushort* y   = (ushort*)p; p += (size_t)TOT_ROWS * DMODEL * 2;      // 62.9 MB
    int*   slot_map = (int*)p;   p += (size_t)TOT_ROWS * 4;
    int*   e1 = (int*)p;   p += (size_t)NTOK * 4;
    int*   e2 = (int*)p;   p += (size_t)NTOK * 4;
    float* g1 = (float*)p; p += (size_t)NTOK * 4;
    float* g2 = (float*)p; p += (size_t)NTOK * 4;
    int*   r1 = (int*)p;   p += (size_t)NTOK * 4;
    int*   r2 = (int*)p;   p += (size_t)NTOK * 4;
    size_t needed = (size_t)(p - (char*)d_ws);
    if (ws_size < needed) return;   // ws too small: bail (validation will flag it)

    hipMemsetAsync(slot_map, 0xFF, (size_t)TOT_ROWS * 4, stream);   // -1 = empty slot

    k_convert_x<<<7680, 256, 0, stream>>>(xd, xc, xbf);
    k_transpose_bf<<<dim3(MLPDIM / 32, DMODEL / 32, NE), dim3(32, 8), 0, stream>>>(w1, w1t, DMODEL, MLPDIM);
    k_transpose_bf<<<dim3(DMODEL / 32, MLPDIM / 32, NE), dim3(32, 8), 0, stream>>>(w2, w2t, MLPDIM, DMODEL);
    k_router<<<NTOK / 4, 256, 0, stream>>>(xd, xc, wrd, wrc, e1, e2, g1, g2);
    k_scan<<<24, 64, 0, stream>>>(e1, e2, slot_map, r1, r2);

    for (int e = 0; e < NE; e++) {
        k_gemm<DMODEL, MLPDIM, true><<<dim3(ROWS_PER_E / 128, MLPDIM / 128), 256, 0, stream>>>(
            xbf, slot_map + (size_t)e * ROWS_PER_E,
            w1t + (size_t)e * MLPDIM * DMODEL, b1 + (size_t)e * MLPDIM, h);
        k_gemm<MLPDIM, DMODEL, false><<<dim3(ROWS_PER_E / 128, DMODEL / 128), 256, 0, stream>>>(
            h, nullptr,
            w2t + (size_t)e * DMODEL * MLPDIM, b2 + (size_t)e * DMODEL,
            y + (size_t)e * ROWS_PER_E * DMODEL);
    }

    k_combine<<<NTOK, 192, 0, stream>>>(y, r1, r2, g1, g2, out);
}